// Round 1
// baseline (123.740 us; speedup 1.0000x reference)
//
#include <hip/hip_runtime.h>
#include <math.h>

// Problem constants: B=32, T=1024, D_IN=64, H=128, NH=4, HD=32, R=3
#define TT 1024

// ---------------------------------------------------------------------------
// K0: combine weights.
//   C[m][d][e] = sum_c theta_w[c][d] * in_proj_w[m*128+e][c],  m in {q,k,v}
//   bq[e] = theta_b . Wq[e] + ipb[e];  bv[e] = theta_b . Wv[e] + ipb[256+e]
// Blocks 0..95: (m, d-pair). Stage the 64KB m-slice of in_proj_w in LDS
// (stride 129 to avoid bank conflicts), coalesced global loads.
// Block 96: biases.
// ---------------------------------------------------------------------------
__global__ __launch_bounds__(256) void k_combine(
    const float* __restrict__ theta_w, const float* __restrict__ theta_b,
    const float* __restrict__ ipw, const float* __restrict__ ipb,
    float* __restrict__ C, float* __restrict__ bqv) {
  __shared__ float s_ipw[128 * 129];
  __shared__ float s_tw2[2][128];
  const int bidx = blockIdx.x;
  const int tid = threadIdx.x;
  if (bidx < 96) {
    const int m = bidx >> 5;       // 0..2
    const int dpair = bidx & 31;   // 0..31 -> d = dpair*2 + dd
    // stage in_proj_w slice (128 rows x 128 cols) into LDS, stride 129
    const float4* g4 = (const float4*)(ipw + m * 128 * 128);
    for (int it = 0; it < 16; ++it) {
      int idx4 = tid + it * 256;
      float4 v = g4[idx4];
      int idx = idx4 * 4;
      int e = idx >> 7;
      int c = idx & 127;
      float* dst = &s_ipw[e * 129 + c];
      dst[0] = v.x; dst[1] = v.y; dst[2] = v.z; dst[3] = v.w;
    }
    {
      int dd = tid >> 7, cc = tid & 127;
      s_tw2[dd][cc] = theta_w[cc * 64 + dpair * 2 + dd];
    }
    __syncthreads();
    const int dd = tid >> 7;
    const int e = tid & 127;
    const float* row = &s_ipw[e * 129];
    const float* tw = s_tw2[dd];
    float acc = 0.f;
    for (int c = 0; c < 128; ++c) acc += tw[c] * row[c];
    C[m * 8192 + (dpair * 2 + dd) * 128 + e] = acc;
  } else {
    // biases
    const int e = tid & 127;
    const int which = tid >> 7;  // 0 -> bq (rows 0..127), 1 -> bv (rows 256..383)
    const int r0 = which ? (256 + e) : e;
    const float* row = ipw + r0 * 128;
    float acc = ipb[r0];
    for (int c = 0; c < 128; ++c) acc += theta_b[c] * row[c];
    bqv[which * 128 + e] = acc;
  }
}

// ---------------------------------------------------------------------------
// K1: fused attention for the last query row. One block per (b, head).
//   prologue: xs_last (7-tap smooth of last x rows) -> q (32) -> r (64)
//   phase 1: t_j = x[b,j,:] . r          (16 lanes/row, float4, coalesced)
//   phase 2: score_s = bandsmooth(t)/rowsum(s); softmax (max + sumexp)
//   phase 3: p~_j = sum_s adj[s,j] p_s   (7-tap with p pre-divided by rowsum)
//   phase 4: u = sum_j p~_j x_j ; o = Cv^T u / denom-normalized + bv
// ---------------------------------------------------------------------------
__global__ __launch_bounds__(256) void k_attn(
    const float* __restrict__ x, const float* __restrict__ C,
    const float* __restrict__ bqv, float* __restrict__ o_out) {
  const int b = blockIdx.x >> 2;
  const int n = blockIdx.x & 3;
  const int tid = threadIdx.x;
  __shared__ float s_xs[64];
  __shared__ float s_q[32];
  __shared__ __align__(16) float s_r[64];
  __shared__ float s_t[TT];
  __shared__ float s_p[TT];
  __shared__ float s_pt[TT];
  __shared__ float s_red[4];
  __shared__ __align__(16) float s_uacc[4][64];
  __shared__ float s_u[64];

  const float* __restrict__ xb = x + (size_t)b * TT * 64;
  const float* Cq = C;
  const float* Ck = C + 8192;
  const float* Cv = C + 16384;

  // ---- prologue: xs_last (row T-1 of Adj*x; taps d=0..3, rowsum 25/12)
  if (tid < 64) {
    float acc = xb[(TT - 1) * 64 + tid]
              + 0.5f        * xb[(TT - 2) * 64 + tid]
              + (1.f / 3.f) * xb[(TT - 3) * 64 + tid]
              + 0.25f       * xb[(TT - 4) * 64 + tid];
    s_xs[tid] = acc * (12.f / 25.f);
  }
  __syncthreads();
  if (tid < 32) {
    float acc = bqv[n * 32 + tid];
    for (int d = 0; d < 64; ++d) acc += Cq[d * 128 + n * 32 + tid] * s_xs[d];
    s_q[tid] = acc;
  }
  __syncthreads();
  if (tid < 64) {
    float acc = 0.f;
    const float* ckr = Ck + tid * 128 + n * 32;
    for (int e = 0; e < 32; ++e) acc += ckr[e] * s_q[e];
    s_r[tid] = acc * 0.17677669529663687f;  // fold in 1/sqrt(HD=32)
  }
  __syncthreads();

  // ---- phase 1: t_j = x_j . r  (group of 16 lanes per row)
  const int g = tid >> 4;   // 0..15
  const int l = tid & 15;   // 0..15
  const float4 r4 = ((const float4*)s_r)[l];
  for (int it = 0; it < 64; ++it) {
    const int j = it * 16 + g;
    const float4 xv = ((const float4*)(xb + j * 64))[l];
    float part = xv.x * r4.x + xv.y * r4.y + xv.z * r4.z + xv.w * r4.w;
    part += __shfl_xor(part, 1);
    part += __shfl_xor(part, 2);
    part += __shfl_xor(part, 4);
    part += __shfl_xor(part, 8);
    if (l == 0) s_t[j] = part;
  }
  __syncthreads();

  // ---- phase 2: scores + softmax (each thread owns 4 consecutive s)
  float sc[4], wsv[4];
  float lmax = -1e30f;
  const int s0 = tid * 4;
  for (int k = 0; k < 4; ++k) {
    const int s = s0 + k;
    float acc = 0.f, wsum = 0.f;
    #pragma unroll
    for (int dj = -3; dj <= 3; ++dj) {
      const int j = s + dj;
      if (j >= 0 && j < TT) {
        const float w = 1.f / (1.f + (float)(dj < 0 ? -dj : dj));
        acc += w * s_t[j];
        wsum += w;
      }
    }
    sc[k] = acc / wsum;
    wsv[k] = wsum;
    lmax = fmaxf(lmax, sc[k]);
  }
  #pragma unroll
  for (int m = 32; m >= 1; m >>= 1) lmax = fmaxf(lmax, __shfl_xor(lmax, m));
  if ((tid & 63) == 0) s_red[tid >> 6] = lmax;
  __syncthreads();
  const float bmax = fmaxf(fmaxf(s_red[0], s_red[1]), fmaxf(s_red[2], s_red[3]));
  __syncthreads();  // all reads of s_red done before rewrite
  float lsum = 0.f;
  for (int k = 0; k < 4; ++k) {
    const float e = expf(sc[k] - bmax);
    lsum += e;
    s_p[s0 + k] = e / wsv[k];  // pre-divide by rowsum(s) for the Adj^T pass
  }
  #pragma unroll
  for (int m = 32; m >= 1; m >>= 1) lsum += __shfl_xor(lsum, m);
  if ((tid & 63) == 0) s_red[tid >> 6] = lsum;
  __syncthreads();
  const float denom = s_red[0] + s_red[1] + s_red[2] + s_red[3];
  const float inv_denom = 1.f / denom;

  // ---- phase 3: p~_j = sum_dj w(|dj|) * p[j+dj]
  for (int k = 0; k < 4; ++k) {
    const int j = s0 + k;
    float acc = 0.f;
    #pragma unroll
    for (int dj = -3; dj <= 3; ++dj) {
      const int s = j + dj;
      if (s >= 0 && s < TT)
        acc += (1.f / (1.f + (float)(dj < 0 ? -dj : dj))) * s_p[s];
    }
    s_pt[j] = acc;
  }
  __syncthreads();

  // ---- phase 4: u = sum_j p~_j * x_j
  float4 u4 = make_float4(0.f, 0.f, 0.f, 0.f);
  for (int it = 0; it < 64; ++it) {
    const int j = it * 16 + g;
    const float pj = s_pt[j];
    const float4 xv = ((const float4*)(xb + j * 64))[l];
    u4.x += pj * xv.x; u4.y += pj * xv.y; u4.z += pj * xv.z; u4.w += pj * xv.w;
  }
  u4.x += __shfl_xor(u4.x, 16); u4.y += __shfl_xor(u4.y, 16);
  u4.z += __shfl_xor(u4.z, 16); u4.w += __shfl_xor(u4.w, 16);
  u4.x += __shfl_xor(u4.x, 32); u4.y += __shfl_xor(u4.y, 32);
  u4.z += __shfl_xor(u4.z, 32); u4.w += __shfl_xor(u4.w, 32);
  const int wv = tid >> 6;
  if ((tid & 63) < 16) ((float4*)s_uacc[wv])[tid & 15] = u4;
  __syncthreads();
  if (tid < 64) {
    s_u[tid] = (s_uacc[0][tid] + s_uacc[1][tid] + s_uacc[2][tid] + s_uacc[3][tid]) * inv_denom;
  }
  __syncthreads();
  if (tid < 32) {
    float acc = bqv[128 + n * 32 + tid];  // bv
    for (int d = 0; d < 64; ++d) acc += Cv[d * 128 + n * 32 + tid] * s_u[d];
    o_out[b * 128 + n * 32 + tid] = acc;
  }
}

// ---------------------------------------------------------------------------
// K2: epilogue. a = o@Wout^T + b; LayerNorm; gelu(ln@w1^T+b1); @w2^T+b2.
// One block per batch row, 128 threads.
// ---------------------------------------------------------------------------
__global__ __launch_bounds__(128) void k_epilogue(
    const float* __restrict__ o, const float* __restrict__ Wout,
    const float* __restrict__ outb, const float* __restrict__ ln_g,
    const float* __restrict__ ln_b, const float* __restrict__ w1,
    const float* __restrict__ b1, const float* __restrict__ w2,
    const float* __restrict__ b2, float* __restrict__ out) {
  const int b = blockIdx.x;
  const int e = threadIdx.x;
  __shared__ float s_o[128], s_ln[128], s_hid[128], s_red[2];
  s_o[e] = o[b * 128 + e];
  __syncthreads();
  float a = outb[e];
  {
    const float* wr = Wout + e * 128;
    for (int f = 0; f < 128; ++f) a += wr[f] * s_o[f];
  }
  // LayerNorm over 128 (2 waves)
  float sum = a;
  #pragma unroll
  for (int m = 32; m >= 1; m >>= 1) sum += __shfl_xor(sum, m);
  if ((e & 63) == 0) s_red[e >> 6] = sum;
  __syncthreads();
  const float mu = (s_red[0] + s_red[1]) * (1.f / 128.f);
  __syncthreads();
  const float d = a - mu;
  float sq = d * d;
  #pragma unroll
  for (int m = 32; m >= 1; m >>= 1) sq += __shfl_xor(sq, m);
  if ((e & 63) == 0) s_red[e >> 6] = sq;
  __syncthreads();
  const float var = (s_red[0] + s_red[1]) * (1.f / 128.f);
  const float ln = d / sqrtf(var + 1e-5f) * ln_g[e] + ln_b[e];
  s_ln[e] = ln;
  __syncthreads();
  float h = b1[e];
  {
    const float* w1r = w1 + e * 128;
    for (int f = 0; f < 128; ++f) h += w1r[f] * s_ln[f];
  }
  h = 0.5f * h * (1.f + erff(h * 0.70710678118654752f));  // exact gelu
  s_hid[e] = h;
  __syncthreads();
  if (e < 2) {
    float acc = b2[e];
    const float* w2r = w2 + e * 128;
    for (int f = 0; f < 128; ++f) acc += w2r[f] * s_hid[f];
    out[b * 2 + e] = acc;
  }
}

extern "C" void kernel_launch(void* const* d_in, const int* in_sizes, int n_in,
                              void* d_out, int out_size, void* d_ws, size_t ws_size,
                              hipStream_t stream) {
  const float* x       = (const float*)d_in[0];
  const float* theta_w = (const float*)d_in[1];
  const float* theta_b = (const float*)d_in[2];
  const float* ipw     = (const float*)d_in[3];
  const float* ipb     = (const float*)d_in[4];
  const float* outw    = (const float*)d_in[5];
  const float* outb    = (const float*)d_in[6];
  const float* ln_g    = (const float*)d_in[7];
  const float* ln_b    = (const float*)d_in[8];
  const float* w1      = (const float*)d_in[9];
  const float* b1      = (const float*)d_in[10];
  const float* w2      = (const float*)d_in[11];
  const float* b2      = (const float*)d_in[12];

  float* ws  = (float*)d_ws;
  float* C   = ws;             // 3*64*128 = 24576 floats
  float* bqv = ws + 24576;     // 256 floats (bq | bv)
  float* o   = ws + 24832;     // 32*128 = 4096 floats

  k_combine<<<97, 256, 0, stream>>>(theta_w, theta_b, ipw, ipb, C, bqv);
  k_attn<<<128, 256, 0, stream>>>(x, C, bqv, o);
  k_epilogue<<<32, 128, 0, stream>>>(o, outw, outb, ln_g, ln_b, w1, b1, w2, b2,
                                     (float*)d_out);
}

// Round 2
// 118.027 us; speedup vs baseline: 1.0484x; 1.0484x over previous
//
#include <hip/hip_runtime.h>
#include <math.h>

// Problem constants: B=32, T=1024, D_IN=64, H=128, NH=4, HD=32, R=3
#define TT 1024

// ---------------------------------------------------------------------------
// k_qr: per-batch prologue. One block per b (32 blocks, 256 thr).
//   xs = last row of Adj*x (taps d=0..3, rowsum 25/12)
//   y  = theta*xs + theta_b                      (128)
//   q  = Wq*y + ipb_q                            (128)
//   z(n) = Wk(n)^T q(n)                          (4 x 128)
//   r(n) = theta^T z(n) / sqrt(32)               (4 x 64)  -> ws
// No combined Cq/Ck matrices needed.
// ---------------------------------------------------------------------------
__global__ __launch_bounds__(256) void k_qr(
    const float* __restrict__ x, const float* __restrict__ theta_w,
    const float* __restrict__ theta_b, const float* __restrict__ ipw,
    const float* __restrict__ ipb, float* __restrict__ r_out) {
  const int b = blockIdx.x;
  const int tid = threadIdx.x;
  __shared__ float s_xs[64];
  __shared__ float s_y[128];
  __shared__ float s_q[128];
  __shared__ float s_z[4][128];
  const float* __restrict__ xb = x + (size_t)b * TT * 64;

  if (tid < 64) {
    float acc = xb[(TT - 1) * 64 + tid]
              + 0.5f        * xb[(TT - 2) * 64 + tid]
              + (1.f / 3.f) * xb[(TT - 3) * 64 + tid]
              + 0.25f       * xb[(TT - 4) * 64 + tid];
    s_xs[tid] = acc * (12.f / 25.f);
  }
  __syncthreads();
  if (tid < 128) {  // y = theta*xs + theta_b
    const float* tr = theta_w + tid * 64;
    float acc = theta_b[tid];
    for (int d = 0; d < 64; ++d) acc += tr[d] * s_xs[d];
    s_y[tid] = acc;
  }
  __syncthreads();
  // q_e = Wq[e,:].y + ipb[e]; 16 groups x 16 lanes, coalesced row reads
  {
    const int g = tid >> 4, l = tid & 15;
    for (int pass = 0; pass < 8; ++pass) {
      const int e = pass * 16 + g;
      const float* wr = ipw + e * 128 + l * 8;
      float acc = 0.f;
      #pragma unroll
      for (int u = 0; u < 8; ++u) acc += wr[u] * s_y[l * 8 + u];
      acc += __shfl_xor(acc, 1);
      acc += __shfl_xor(acc, 2);
      acc += __shfl_xor(acc, 4);
      acc += __shfl_xor(acc, 8);
      if (l == 0) s_q[e] = acc + ipb[e];
    }
  }
  __syncthreads();
  // z[n][c] = sum_e Wk[128+n*32+e, c] * q[n*32+e]; coalesced along c
  for (int rep = 0; rep < 2; ++rep) {
    const int idx = tid + rep * 256;
    const int n = idx >> 7, c = idx & 127;
    const float* qn = &s_q[n * 32];
    float acc = 0.f;
    for (int e = 0; e < 32; ++e) acc += ipw[(128 + n * 32 + e) * 128 + c] * qn[e];
    s_z[n][c] = acc;
  }
  __syncthreads();
  // r[n][d] = sum_c theta[c,d] z[n][c]; coalesced along d
  {
    const int n = tid >> 6, d = tid & 63;
    const float* zn = s_z[n];
    float acc = 0.f;
    for (int c = 0; c < 128; ++c) acc += theta_w[c * 64 + d] * zn[c];
    r_out[(b * 4 + n) * 64 + d] = acc * 0.17677669529663687f;  // fold 1/sqrt(32)
  }
}

// ---------------------------------------------------------------------------
// k_t: t[b,n,j] = x[b,j,:] . r[b,n,:]. Grid = 32 b x 16 chunks = 512 blocks.
// Each block: 64 rows, 16 lanes/row float4 (coalesced), all 4 heads per read.
// ---------------------------------------------------------------------------
__global__ __launch_bounds__(256) void k_t(
    const float* __restrict__ x, const float* __restrict__ r_in,
    float* __restrict__ t_out) {
  const int b = blockIdx.x >> 4;
  const int chunk = blockIdx.x & 15;
  const int tid = threadIdx.x;
  __shared__ __align__(16) float s_r[256];
  s_r[tid] = r_in[b * 256 + tid];
  __syncthreads();
  const int g = tid >> 4, l = tid & 15;
  const float4 r0 = ((const float4*)(s_r +   0))[l];
  const float4 r1 = ((const float4*)(s_r +  64))[l];
  const float4 r2 = ((const float4*)(s_r + 128))[l];
  const float4 r3 = ((const float4*)(s_r + 192))[l];
  const float* __restrict__ xb = x + ((size_t)b * TT + chunk * 64) * 64;
  for (int it = 0; it < 4; ++it) {
    const int jj = it * 16 + g;
    const float4 xv = ((const float4*)(xb + jj * 64))[l];
    float p0 = xv.x * r0.x + xv.y * r0.y + xv.z * r0.z + xv.w * r0.w;
    float p1 = xv.x * r1.x + xv.y * r1.y + xv.z * r1.z + xv.w * r1.w;
    float p2 = xv.x * r2.x + xv.y * r2.y + xv.z * r2.z + xv.w * r2.w;
    float p3 = xv.x * r3.x + xv.y * r3.y + xv.z * r3.z + xv.w * r3.w;
    #pragma unroll
    for (int m = 1; m <= 8; m <<= 1) {
      p0 += __shfl_xor(p0, m);
      p1 += __shfl_xor(p1, m);
      p2 += __shfl_xor(p2, m);
      p3 += __shfl_xor(p3, m);
    }
    if (l == 0) {
      const int j = chunk * 64 + jj;
      t_out[(b * 4 + 0) * TT + j] = p0;
      t_out[(b * 4 + 1) * TT + j] = p1;
      t_out[(b * 4 + 2) * TT + j] = p2;
      t_out[(b * 4 + 3) * TT + j] = p3;
    }
  }
}

// ---------------------------------------------------------------------------
// k_sm: per (b,n): smooth scores, softmax, Adj^T-smooth. Writes p~ * 1/denom
// IN PLACE over t (t fully staged to LDS first). 128 blocks x 256 thr.
// ---------------------------------------------------------------------------
__global__ __launch_bounds__(256) void k_sm(float* __restrict__ t_pt) {
  const int bn = blockIdx.x;
  const int tid = threadIdx.x;
  __shared__ __align__(16) float s_t[TT];
  __shared__ float s_p[TT];
  __shared__ float s_red[4];
  ((float4*)s_t)[tid] = ((const float4*)(t_pt + bn * TT))[tid];
  __syncthreads();

  float sc[4], wsv[4];
  float lmax = -1e30f;
  const int s0 = tid * 4;
  for (int k = 0; k < 4; ++k) {
    const int s = s0 + k;
    float acc = 0.f, wsum = 0.f;
    #pragma unroll
    for (int dj = -3; dj <= 3; ++dj) {
      const int j = s + dj;
      if (j >= 0 && j < TT) {
        const float w = 1.f / (1.f + (float)(dj < 0 ? -dj : dj));
        acc += w * s_t[j];
        wsum += w;
      }
    }
    sc[k] = acc / wsum;
    wsv[k] = wsum;
    lmax = fmaxf(lmax, sc[k]);
  }
  #pragma unroll
  for (int m = 32; m >= 1; m >>= 1) lmax = fmaxf(lmax, __shfl_xor(lmax, m));
  if ((tid & 63) == 0) s_red[tid >> 6] = lmax;
  __syncthreads();
  const float bmax = fmaxf(fmaxf(s_red[0], s_red[1]), fmaxf(s_red[2], s_red[3]));
  __syncthreads();
  float lsum = 0.f;
  for (int k = 0; k < 4; ++k) {
    const float e = expf(sc[k] - bmax);
    lsum += e;
    s_p[s0 + k] = e / wsv[k];  // pre-divide by rowsum for the Adj^T pass
  }
  #pragma unroll
  for (int m = 32; m >= 1; m >>= 1) lsum += __shfl_xor(lsum, m);
  if ((tid & 63) == 0) s_red[tid >> 6] = lsum;
  __syncthreads();
  const float inv_denom = 1.f / (s_red[0] + s_red[1] + s_red[2] + s_red[3]);
  // p~_j = sum_dj w(|dj|) p[j+dj]; fold inv_denom; overwrite t in global
  for (int k = 0; k < 4; ++k) {
    const int j = s0 + k;
    float acc = 0.f;
    #pragma unroll
    for (int dj = -3; dj <= 3; ++dj) {
      const int s = j + dj;
      if (s >= 0 && s < TT)
        acc += (1.f / (1.f + (float)(dj < 0 ? -dj : dj))) * s_p[s];
    }
    t_pt[bn * TT + j] = acc * inv_denom;
  }
}

// ---------------------------------------------------------------------------
// k_u: partial u[b,chunk,n,d] = sum_{j in chunk} p~[b,n,j] x[b,j,d].
// Grid = 512 blocks. x chunk staged in LDS (bank-conflict-free: 2-way = free).
// ---------------------------------------------------------------------------
__global__ __launch_bounds__(256) void k_u(
    const float* __restrict__ x, const float* __restrict__ pt_in,
    float* __restrict__ up_out) {
  const int b = blockIdx.x >> 4;
  const int chunk = blockIdx.x & 15;
  const int tid = threadIdx.x;
  __shared__ __align__(16) float s_x[64][64];
  __shared__ float s_p[4][64];
  const float* __restrict__ xb = x + ((size_t)b * TT + chunk * 64) * 64;
  #pragma unroll
  for (int it = 0; it < 4; ++it) {
    const int i4 = tid + it * 256;
    ((float4*)&s_x[0][0])[i4] = ((const float4*)xb)[i4];
  }
  {
    const int n = tid >> 6, jj = tid & 63;
    s_p[n][jj] = pt_in[(b * 4 + n) * TT + chunk * 64 + jj];
  }
  __syncthreads();
  const int n = tid >> 6, d = tid & 63;
  float acc = 0.f;
  for (int jj = 0; jj < 64; ++jj) acc += s_p[n][jj] * s_x[jj][d];
  up_out[((b * 16 + chunk) * 4 + n) * 64 + d] = acc;
}

// ---------------------------------------------------------------------------
// k_tail: per b: reduce u over chunks; o = Wv*(theta*u + theta_b) + ipb_v;
// a = Wout*o + outb; LayerNorm; gelu(W1*ln+b1); W2*hid+b2. 32 blocks x 128 thr.
// ---------------------------------------------------------------------------
__global__ __launch_bounds__(128) void k_tail(
    const float* __restrict__ up_in, const float* __restrict__ theta_w,
    const float* __restrict__ theta_b, const float* __restrict__ ipw,
    const float* __restrict__ ipb, const float* __restrict__ Wout,
    const float* __restrict__ outb, const float* __restrict__ ln_g,
    const float* __restrict__ ln_b, const float* __restrict__ w1,
    const float* __restrict__ b1, const float* __restrict__ w2,
    const float* __restrict__ b2, float* __restrict__ out) {
  const int b = blockIdx.x;
  const int tid = threadIdx.x;
  __shared__ float s_u[256];      // [n][d]
  __shared__ float s_w[4][128];   // theta*u + theta_b per head
  __shared__ float s_o[128], s_ln[128], s_hid[128], s_red[2];

  // reduce partials: s_u[idx] = sum_c up[(b*16+c)*256 + idx]
  for (int rep = 0; rep < 2; ++rep) {
    const int idx = tid + rep * 128;
    float acc = 0.f;
    for (int c = 0; c < 16; ++c) acc += up_in[(b * 16 + c) * 256 + idx];
    s_u[idx] = acc;
  }
  __syncthreads();
  // w[n][c] = theta[c,:].u(n) + theta_b[c]
  for (int rep = 0; rep < 4; ++rep) {
    const int idx = tid + rep * 128;
    const int n = idx >> 7, c = idx & 127;
    const float* tr = theta_w + c * 64;
    const float* un = &s_u[n * 64];
    float acc = theta_b[c];
    for (int d = 0; d < 64; ++d) acc += tr[d] * un[d];
    s_w[n][c] = acc;
  }
  __syncthreads();
  // o_e = Wv[256+e,:].w(n(e)) + ipb[256+e]
  {
    const int e = tid, n = e >> 5;
    const float* wr = ipw + (256 + e) * 128;
    const float* wn = s_w[n];
    float acc = ipb[256 + e];
    for (int c = 0; c < 128; ++c) acc += wr[c] * wn[c];
    s_o[e] = acc;
  }
  __syncthreads();
  // epilogue
  const int e = tid;
  float a = outb[e];
  {
    const float* wr = Wout + e * 128;
    for (int f = 0; f < 128; ++f) a += wr[f] * s_o[f];
  }
  float sum = a;
  #pragma unroll
  for (int m = 32; m >= 1; m >>= 1) sum += __shfl_xor(sum, m);
  if ((e & 63) == 0) s_red[e >> 6] = sum;
  __syncthreads();
  const float mu = (s_red[0] + s_red[1]) * (1.f / 128.f);
  __syncthreads();
  const float d = a - mu;
  float sq = d * d;
  #pragma unroll
  for (int m = 32; m >= 1; m >>= 1) sq += __shfl_xor(sq, m);
  if ((e & 63) == 0) s_red[e >> 6] = sq;
  __syncthreads();
  const float var = (s_red[0] + s_red[1]) * (1.f / 128.f);
  const float ln = d / sqrtf(var + 1e-5f) * ln_g[e] + ln_b[e];
  s_ln[e] = ln;
  __syncthreads();
  float h = b1[e];
  {
    const float* w1r = w1 + e * 128;
    for (int f = 0; f < 128; ++f) h += w1r[f] * s_ln[f];
  }
  h = 0.5f * h * (1.f + erff(h * 0.70710678118654752f));
  s_hid[e] = h;
  __syncthreads();
  if (e < 2) {
    float acc = b2[e];
    const float* w2r = w2 + e * 128;
    for (int f = 0; f < 128; ++f) acc += w2r[f] * s_hid[f];
    out[b * 2 + e] = acc;
  }
}

extern "C" void kernel_launch(void* const* d_in, const int* in_sizes, int n_in,
                              void* d_out, int out_size, void* d_ws, size_t ws_size,
                              hipStream_t stream) {
  const float* x       = (const float*)d_in[0];
  const float* theta_w = (const float*)d_in[1];
  const float* theta_b = (const float*)d_in[2];
  const float* ipw     = (const float*)d_in[3];
  const float* ipb     = (const float*)d_in[4];
  const float* outw    = (const float*)d_in[5];
  const float* outb    = (const float*)d_in[6];
  const float* ln_g    = (const float*)d_in[7];
  const float* ln_b    = (const float*)d_in[8];
  const float* w1      = (const float*)d_in[9];
  const float* b1      = (const float*)d_in[10];
  const float* w2      = (const float*)d_in[11];
  const float* b2      = (const float*)d_in[12];

  float* ws = (float*)d_ws;
  float* r  = ws;                 // 32*4*64      = 8192 floats
  float* t  = ws + 8192;          // 32*4*1024    = 131072 (reused as p~)
  float* up = ws + 8192 + 131072; // 32*16*4*64   = 131072

  k_qr  <<< 32, 256, 0, stream>>>(x, theta_w, theta_b, ipw, ipb, r);
  k_t   <<<512, 256, 0, stream>>>(x, r, t);
  k_sm  <<<128, 256, 0, stream>>>(t);
  k_u   <<<512, 256, 0, stream>>>(x, t, up);
  k_tail<<< 32, 128, 0, stream>>>(up, theta_w, theta_b, ipw, ipb, outw, outb,
                                  ln_g, ln_b, w1, b1, w2, b2, (float*)d_out);
}